// Round 4
// baseline (441.369 us; speedup 1.0000x reference)
//
#include <hip/hip_runtime.h>

// LSTM via split-bf16 MFMA, round 4. B=4096, T=512, I=10, H=32, O=1.
// Gates i,f,g,o. R3 was latency-bound (1590 cyc/step/SIMD: 826 VALU-busy,
// 198 MFMA, ~570 idle) with a bloated VALU bill (split8, pack/unpack perms).
// R4: h exchanged through LDS as bf16 hi/lo planes written with ds_write_b16
// directly in MFMA-A-fragment order (reader = 2x ds_read_b128, no perms);
// x quantized to bf16 once (W*x_hat via Whi+Wlo, exact in W); preacts taken
// straight from a single bias-initialized MFMA C chain; exp2f transcendentals.
//
// Structure (unchanged from R3): block = 4 waves = 16 batches. Wave w owns
// hidden slice [8w,8w+8) as 2 N-tiles of mfma_f32_16x16x32_bf16:
//   tile0 cols: c<8 -> i_{8w+c}, c>=8 -> f_{8w+c-8}
//   tile1 cols: c<8 -> g_{8w+c}, c>=8 -> o_{8w+c-8}
// C layout: col=lane&15 (gate col), row=quad*4+reg (batch).
// A layout: A[m=lane&15 (batch)][k=quad*8+j (hidden)].
// LDS h planes: [2 bufs][16 batches][stride 40 bf16] (pad -> 2-way banks, free).

#define T_SZ 512
#define I_SZ 10
#define H_SZ 32
#define HSTR 40   // bf16 stride per batch row (80 B)

typedef short bf16x8 __attribute__((ext_vector_type(8)));
typedef float f32x4  __attribute__((ext_vector_type(4)));
typedef int   i32x4  __attribute__((ext_vector_type(4)));

union FB { i32x4 i; bf16x8 b; };
static __device__ __forceinline__ bf16x8 fragv(i32x4 v) { FB u; u.i = v; return u.b; }
static __device__ __forceinline__ bf16x8 frag4(int a, int b, int c, int d) {
    FB u; u.i = (i32x4){a, b, c, d}; return u.b;
}

// low16 = top16(e), high16 = top16(o)  (truncation bf16 pack of a pair)
static __device__ __forceinline__ int pack_hi16(float o, float e) {
    return (int)__builtin_amdgcn_perm(__float_as_uint(o), __float_as_uint(e), 0x07060302u);
}

// truncation split of 8 fp32 -> bf16-hi frag + bf16-lo frag (weights, one-time)
static __device__ __forceinline__ void split8(const float w[8], int hi[4], int lo[4]) {
    #pragma unroll
    for (int j = 0; j < 4; ++j) {
        float e = w[2*j], o = w[2*j+1];
        float eh = __uint_as_float(__float_as_uint(e) & 0xFFFF0000u);
        float oh = __uint_as_float(__float_as_uint(o) & 0xFFFF0000u);
        hi[j] = pack_hi16(o, e);
        lo[j] = pack_hi16(o - oh, e - eh);
    }
}

static __device__ __forceinline__ float dpp_ror8(float v) {
    // 16-lane row rotate by 8: lane c receives lane (c+8)&15 -> partner column
    return __int_as_float(__builtin_amdgcn_mov_dpp(__float_as_int(v), 0x128, 0xF, 0xF, true));
}

#define MFMA(A, B, C) __builtin_amdgcn_mfma_f32_16x16x32_bf16((A), (B), (C), 0, 0, 0)

__global__ __launch_bounds__(256, 1)
void lstm_mfma(const float* __restrict__ x, const float* __restrict__ W_ih,
               const float* __restrict__ W_hh, const float* __restrict__ b_ih,
               const float* __restrict__ b_hh, const float* __restrict__ W_dense,
               const float* __restrict__ b_dense, float* __restrict__ out)
{
    const int tid   = threadIdx.x;
    const int wv    = tid >> 6;
    const int lane  = tid & 63;
    const int col   = lane & 15;
    const int quad  = lane >> 4;
    const int bbase = blockIdx.x * 16;

    const int  jloc = col & 7;
    const int  hid  = 8 * wv + jloc;
    const bool isA  = (col < 8);
    const int  row0 = (isA ? 0 : 32) + hid;    // i | f
    const int  row1 = (isA ? 64 : 96) + hid;   // g | o

    // ---- weight B-fragments (one-time) ----
    int bhh0h[4], bhh0l[4], bhh1h[4], bhh1l[4];
    {
        float w[8];
        const float* p = W_hh + row0 * H_SZ + 8 * quad;
        #pragma unroll
        for (int j = 0; j < 4; ++j) { float2 v = *(const float2*)(p + 2*j); w[2*j] = v.x; w[2*j+1] = v.y; }
        split8(w, bhh0h, bhh0l);
        p = W_hh + row1 * H_SZ + 8 * quad;
        #pragma unroll
        for (int j = 0; j < 4; ++j) { float2 v = *(const float2*)(p + 2*j); w[2*j] = v.x; w[2*j+1] = v.y; }
        split8(w, bhh1h, bhh1l);
    }
    int bih0h[4], bih0l[4], bih1h[4], bih1l[4];
    {
        float w[8];
        #pragma unroll
        for (int j = 0; j < 8; ++j) w[j] = 0.0f;
        if (quad == 0) {
            const float* p = W_ih + row0 * I_SZ;
            #pragma unroll
            for (int j = 0; j < 4; ++j) { float2 v = *(const float2*)(p + 2*j); w[2*j] = v.x; w[2*j+1] = v.y; }
        } else if (quad == 1) {
            float2 v = *(const float2*)(W_ih + row0 * I_SZ + 8); w[0] = v.x; w[1] = v.y;
        }
        split8(w, bih0h, bih0l);
        #pragma unroll
        for (int j = 0; j < 8; ++j) w[j] = 0.0f;
        if (quad == 0) {
            const float* p = W_ih + row1 * I_SZ;
            #pragma unroll
            for (int j = 0; j < 4; ++j) { float2 v = *(const float2*)(p + 2*j); w[2*j] = v.x; w[2*j+1] = v.y; }
        } else if (quad == 1) {
            float2 v = *(const float2*)(W_ih + row1 * I_SZ + 8); w[0] = v.x; w[1] = v.y;
        }
        split8(w, bih1h, bih1l);
    }

    const float bias0  = b_ih[row0] + b_hh[row0];
    const float bias1  = b_ih[row1] + b_hh[row1];
    const f32x4 biasv0 = {bias0, bias0, bias0, bias0};
    const f32x4 biasv1 = {bias1, bias1, bias1, bias1};

    // ---- LDS h planes: bf16 hi/lo, A-frag order, padded stride ----
    __shared__ __attribute__((aligned(16))) short sh_hi[2][16 * HSTR];
    __shared__ __attribute__((aligned(16))) short sh_lo[2][16 * HSTR];
    {
        int* z0 = (int*)&sh_hi[0][0];
        int* z1 = (int*)&sh_lo[0][0];
        #pragma unroll
        for (int i = 0; i < (2 * 16 * HSTR / 2 + 255) / 256; ++i) {
            int idx = tid + i * 256;
            if (idx < 2 * 16 * HSTR / 2) { z0[idx] = 0; z1[idx] = 0; }
        }
    }
    __syncthreads();

    // ---- per-lane activation constants ----
    const float m1 = isA ? -2.8853901f : -1.4426950f;   // exp2 scale for s1 (tanh|sigm)
    const float sc = isA ?  2.0f : 1.0f;
    const float so = isA ? -1.0f : 0.0f;
    const float nL = -1.4426950f;                        // -log2(e)

    // ---- x stream (batch = col; same addr across quads, L1 broadcast) ----
    const float* xrow = x + (size_t)(bbase + col) * (T_SZ * I_SZ);
    float2 xc0 = *(const float2*)(xrow + 0);
    float2 xc1 = *(const float2*)(xrow + 2);
    float2 xc2 = *(const float2*)(xrow + 4);
    float2 xc3 = *(const float2*)(xrow + 6);
    float2 xc4 = *(const float2*)(xrow + 8);

    f32x4 c4 = {0.f, 0.f, 0.f, 0.f};
    const bool q0 = (quad == 0), q1 = (quad == 1);

    #pragma unroll 2
    for (int t = 0; t < T_SZ; ++t) {
        const int rb = t & 1;
        const int wb = rb ^ 1;

        // h fragment reads (issue first; consumed after x-chain)
        const short* hp = &sh_hi[rb][col * HSTR + 8 * quad];
        const short* lp = &sh_lo[rb][col * HSTR + 8 * quad];
        i32x4 hhi_ = *(const i32x4*)hp;
        i32x4 hlo_ = *(const i32x4*)lp;

        // pack current x to bf16 A-frag (quad0: k0..7, quad1: k8,9)
        int p0 = pack_hi16(xc0.y, xc0.x);
        int p1 = pack_hi16(xc1.y, xc1.x);
        int p2 = pack_hi16(xc2.y, xc2.x);
        int p3 = pack_hi16(xc3.y, xc3.x);
        int p4 = pack_hi16(xc4.y, xc4.x);
        bf16x8 xf = frag4(q0 ? p0 : (q1 ? p4 : 0),
                          q0 ? p1 : 0, q0 ? p2 : 0, q0 ? p3 : 0);

        // prefetch next x
        if (t + 1 < T_SZ) {
            const float* xr = xrow + (t + 1) * I_SZ;
            xc0 = *(const float2*)(xr + 0);
            xc1 = *(const float2*)(xr + 2);
            xc2 = *(const float2*)(xr + 4);
            xc3 = *(const float2*)(xr + 6);
            xc4 = *(const float2*)(xr + 8);
        }

        // x-part: W*x_hat = Whi*x_hat + Wlo*x_hat (exact in W), bias in C-init
        f32x4 a0 = MFMA(xf, frag4(bih0h[0], bih0h[1], bih0h[2], bih0h[3]), biasv0);
        f32x4 a1 = MFMA(xf, frag4(bih1h[0], bih1h[1], bih1h[2], bih1h[3]), biasv1);
        a0 = MFMA(xf, frag4(bih0l[0], bih0l[1], bih0l[2], bih0l[3]), a0);
        a1 = MFMA(xf, frag4(bih1l[0], bih1l[1], bih1l[2], bih1l[3]), a1);

        // h-part, 3-term: Whi*hhi + Whi*hlo + Wlo*hhi
        bf16x8 hhi = fragv(hhi_), hlo = fragv(hlo_);
        a0 = MFMA(hhi, frag4(bhh0h[0], bhh0h[1], bhh0h[2], bhh0h[3]), a0);
        a1 = MFMA(hhi, frag4(bhh1h[0], bhh1h[1], bhh1h[2], bhh1h[3]), a1);
        a0 = MFMA(hlo, frag4(bhh0h[0], bhh0h[1], bhh0h[2], bhh0h[3]), a0);
        a1 = MFMA(hlo, frag4(bhh1h[0], bhh1h[1], bhh1h[2], bhh1h[3]), a1);
        a0 = MFMA(hhi, frag4(bhh0l[0], bhh0l[1], bhh0l[2], bhh0l[3]), a0);
        a1 = MFMA(hhi, frag4(bhh1l[0], bhh1l[1], bhh1l[2], bhh1l[3]), a1);

        // activations + state + h store (batch = 4*quad + r)
        #pragma unroll
        for (int r = 0; r < 4; ++r) {
            float pa = a0[r];                       // i | f preact
            float pb = a1[r];                       // g | o preact
            float s0 = __builtin_amdgcn_rcpf(1.0f + exp2f(nL * pa));   // i | f
            float rr = __builtin_amdgcn_rcpf(1.0f + exp2f(m1 * pb));
            float s1 = fmaf(sc, rr, so);            // g | o
            float fg = dpp_ror8(s0);                // f (valid on isA lanes)
            float og = dpp_ror8(s1);                // o
            float cn = fmaf(fg, c4[r], s0 * s1);
            c4[r] = cn;
            float tr = __builtin_amdgcn_rcpf(1.0f + exp2f(-2.8853901f * cn));
            float h  = fmaf(og + og, tr, -og);      // o * tanh(c)
            if (isA) {
                unsigned hb  = __float_as_uint(h);
                float    hif = __uint_as_float(hb & 0xFFFF0000u);
                float    lo  = h - hif;
                sh_hi[wb][(4 * quad + r) * HSTR + hid] = (short)(hb >> 16);
                sh_lo[wb][(4 * quad + r) * HSTR + hid] = (short)(__float_as_uint(lo) >> 16);
            }
        }
        __syncthreads();
    }

    // ---- dense head: final h in buffer 0 (T even) ----
    if (wv == 0 && lane < 16) {
        float acc = b_dense[0];
        #pragma unroll 4
        for (int j = 0; j < H_SZ; ++j) {
            unsigned hi = (unsigned short)sh_hi[0][lane * HSTR + j];
            unsigned lo = (unsigned short)sh_lo[0][lane * HSTR + j];
            float hv = __uint_as_float(hi << 16) + __uint_as_float(lo << 16);
            acc += hv * W_dense[j];
        }
        out[bbase + lane] = acc;
    }
}

extern "C" void kernel_launch(void* const* d_in, const int* in_sizes, int n_in,
                              void* d_out, int out_size, void* d_ws, size_t ws_size,
                              hipStream_t stream) {
    const float* x       = (const float*)d_in[0];
    const float* W_ih    = (const float*)d_in[1];
    const float* W_hh    = (const float*)d_in[2];
    const float* b_ih    = (const float*)d_in[3];
    const float* b_hh    = (const float*)d_in[4];
    const float* W_dense = (const float*)d_in[5];
    const float* b_dense = (const float*)d_in[6];
    float* out = (float*)d_out;

    // 256 blocks x 4 waves = 1024 waves (1/SIMD), 16 batches/block
    lstm_mfma<<<dim3(256), dim3(256), 0, stream>>>(
        x, W_ih, W_hh, b_ih, b_hh, W_dense, b_dense, out);
}